// Round 1
// baseline (113.561 us; speedup 1.0000x reference)
//
#include <hip/hip_runtime.h>

// CCN_2D on MI355X. N=256 vertices, K=16, C0=16, H=32.
// Facts (validated by exact passes R1-R10):
//  * CH rows one-hot => T_t[a][b][c] = Fin[j_t, P_t[a], P_t[b], c].
//  * A = I_16 collapses contract18 to 6 effective weight matrices.
//  * P_t[t] = -1 (no self-loops) => c17 / d_ttt terms vanish.
//  * Layer-1 input is broadcast of X => rank-1 closed form, no gathers.
//  * F1 channel-interleaved: chunk (i*16+q)*128 + c4*16 + p holds channels
//    4c4..4c4+3 of F1[i][p][q][:] (16 B stride on lane-varying p).
// Structure ladder (measured): 2 plain launches (R6, 107.7) beats 3 launches
// (113.9), coop launch (154.5), and 1 launch w/ device-scope flags (122.4).
// Measured window = 2x ~43.2us harness ws-poison fills (untouchable) + ~20us
// of kernels. Kernels are VALU-issue-bound (1 block/CU, 2 waves/SIMD).
// This round: replace the readlane-broadcast matmuls (2 VALU/fma: readlane +
// fma) with scalar-pipe weight loads (uniform float4 -> s_load_dwordx4,
// co-issues with VALU => 1 VALU/fma). Of the 6 effective weight slices only
// Wsb is a linear combination; the rest are verbatim W1/W2 slices readable
// straight from global (the x16 on Wt2 folds exactly into the coefficient:
// power of two => bit-exact). l1 blocks 0-1 precompute Wsb2 (4 KB) into ws;
// l2 drops its E2 LDS preprocessing except a 12 KB verbatim copy of the 3
// epilogue slices (lane-varying index => LDS stays right for those).

constexpr int KN = 16, HH = 32, NV = 256, C2 = 32;

// ACC[h] += COEF(ci) * W[ci][h], ci in [0, 8*NB), W row-major [c][32] in
// GLOBAL memory, address wave-uniform => compiler emits scalar (SMEM) loads
// that co-issue with the VALU fma stream. 1 VALU instruction per fma.
#define MM_SL(WPTR, NB, COEF_EXPR, ACC) do {                                   \
    const float4* W4_ = (const float4*)(WPTR);                                 \
    _Pragma("unroll")                                                          \
    for (int B = 0; B < (NB); ++B) {                                           \
        _Pragma("unroll")                                                      \
        for (int cc = 0; cc < 8; ++cc) {                                       \
            const int ci = B * 8 + cc;                                         \
            const float cf_ = (COEF_EXPR);                                     \
            _Pragma("unroll")                                                  \
            for (int h4 = 0; h4 < 8; ++h4) {                                   \
                const float4 w_ = W4_[ci * 8 + h4];                            \
                (ACC)[4*h4+0] = fmaf(cf_, w_.x, (ACC)[4*h4+0]);                \
                (ACC)[4*h4+1] = fmaf(cf_, w_.y, (ACC)[4*h4+1]);                \
                (ACC)[4*h4+2] = fmaf(cf_, w_.z, (ACC)[4*h4+2]);                \
                (ACC)[4*h4+3] = fmaf(cf_, w_.w, (ACC)[4*h4+3]);                \
            }                                                                  \
        }                                                                      \
    }                                                                          \
} while (0)

// ---------------- layer 1 ----------------
// E1 slices (512 floats each): 0:Wsb 1:Wab 2:W16 3:(dead) 4:Wtb 5:Wal
// pre = vy*(m*Y0.Wsb) + (m^2*Y0).Wab + vy*(Y0.W16) + Z2.Wt2 + Z4.Wtb + dxy*Z5.Wal
// Wt2 = 16*W1[2*512+..] applied via MM_SL on W1 directly with cf = 16*Z2.
// Output layout (float4 chunks): F1c chunk index = (i*16+q)*128 + c4*16 + p,
// holding channels c4*4..c4*4+3 of logical F1[i][p][q][:]. (q,p) = (y,x).
__global__ __launch_bounds__(512)
void ccn_l1(const float* __restrict__ X, const int* __restrict__ nbrs,
            const float* __restrict__ W1, const float* __restrict__ bias,
            float* __restrict__ F1c, float* __restrict__ outz,
            const float* __restrict__ W2f, float* __restrict__ Wsb2)
{
    __shared__ float sE1[6 * 512];       // 12 KB
    __shared__ float sPP2[8 * 256 * 4];  // 32 KB, channel-major [h4][cell][4]
    __shared__ float sX[16][20];
    __shared__ float sV[16][164];        // 5 matvec results x 32 per group
    __shared__ int   s_nbi[16];
    __shared__ int   s_nbj[16][17];
    __shared__ int   s_P[16][16];
    __shared__ int   s_vm[16];
    __shared__ float s_m[16];

    const int tid  = threadIdx.x;
    const int i    = ((blockIdx.x & 7) << 5) | (blockIdx.x >> 3);  // XCD swizzle

    if (blockIdx.x == 0 && tid == 0) outz[0] = 0.f;   // zero accumulator for l2

    // blocks 0,1: precompute the one combined layer-2 slice Wsb2 (1024 floats)
    // into the workspace so l2 can stream it through the scalar pipe.
    // Expression identical to the old in-l2 sE2[u] computation (bit-exact).
    if (blockIdx.x < 2) {
        const int u = (blockIdx.x << 9) | tid;
        float acc = 0.f;
        #pragma unroll
        for (int g = 6; g < 15; ++g) acc += W2f[g * 1024 + u];
        Wsb2[u] = 16.f * W2f[u] + W2f[5 * 1024 + u] + 16.f * acc;
    }

    if (tid < 16) s_nbi[tid] = nbrs[i * 16 + tid];
    __syncthreads();  // B0

    if (tid < 256) {
        const int t = tid >> 4, y = tid & 15;
        const int j = s_nbi[t];
        s_nbj[t][y] = nbrs[j * 16 + y];
        sX[t][y]    = X[j * 16 + y];
    } else {
        const int u = tid - 256;       // E1 entries 0..255
        float acc = 0.f;
        #pragma unroll
        for (int g = 6; g < 15; ++g) acc += W1[g * 512 + u];
        sE1[u]        = 16.f * W1[u] + W1[5 * 512 + u] + 16.f * acc;
        sE1[512 + u]  = W1[512 + u];
        sE1[1024 + u] = W1[15 * 512 + u];
        sE1[2048 + u] = W1[3 * 512 + u];
        sE1[2560 + u] = W1[4 * 512 + u];
    }
    __syncthreads();  // B1

    if (tid < 256) {
        const int t = tid >> 4, y = tid & 15;
        const int tgt = s_nbi[y];
        int p = -1;
        #pragma unroll
        for (int q = 0; q < 16; ++q) if (s_nbj[t][q] == tgt) p = q;
        s_P[t][y] = p;
        unsigned long long bal = __ballot(p >= 0);
        if (y == 0) {
            int vm = (int)((bal >> ((t & 3) * 16)) & 0xFFFFull);
            s_vm[t] = vm;
            s_m[t]  = (float)__popc(vm);
        }
    } else {
        const int u = tid;             // E1 entries 256..511
        float acc = 0.f;
        #pragma unroll
        for (int g = 6; g < 15; ++g) acc += W1[g * 512 + u];
        sE1[u]        = 16.f * W1[u] + W1[5 * 512 + u] + 16.f * acc;
        sE1[512 + u]  = W1[512 + u];
        sE1[1024 + u] = W1[15 * 512 + u];
        sE1[2048 + u] = W1[3 * 512 + u];
        sE1[2560 + u] = W1[4 * 512 + u];
    }
    __syncthreads();  // B2

    if (tid < 256) {
        // ---- half A: Z4/Z5 + 5 cooperative matvecs (lane y -> h=2y,2y+1) ----
        const int t = tid >> 4, y = tid & 15, x = t;
        float Y0[16];
        #pragma unroll
        for (int c4 = 0; c4 < 4; ++c4) {
            float4 v = *(const float4*)&sX[t][4 * c4];
            Y0[4*c4+0] = v.x; Y0[4*c4+1] = v.y; Y0[4*c4+2] = v.z; Y0[4*c4+3] = v.w;
        }
        float Z4[16], Z5[16];
        #pragma unroll
        for (int c = 0; c < 16; ++c) { Z4[c] = 0.f; Z5[c] = 0.f; }
        #pragma unroll
        for (int tp = 0; tp < 16; ++tp) {
            const int vm = s_vm[tp];
            const float mt = s_m[tp];
            const float fb = ((vm >> x) & 1) ? mt : 0.f;
            const float f5 = mt * mt;
            #pragma unroll
            for (int c4 = 0; c4 < 4; ++c4) {
                float4 v = *(const float4*)&sX[tp][4 * c4];
                Z4[4*c4+0] = fmaf(fb, v.x, Z4[4*c4+0]);
                Z4[4*c4+1] = fmaf(fb, v.y, Z4[4*c4+1]);
                Z4[4*c4+2] = fmaf(fb, v.z, Z4[4*c4+2]);
                Z4[4*c4+3] = fmaf(fb, v.w, Z4[4*c4+3]);
                Z5[4*c4+0] = fmaf(f5, v.x, Z5[4*c4+0]);
                Z5[4*c4+1] = fmaf(f5, v.y, Z5[4*c4+1]);
                Z5[4*c4+2] = fmaf(f5, v.z, Z5[4*c4+2]);
                Z5[4*c4+3] = fmaf(f5, v.w, Z5[4*c4+3]);
            }
        }
        const float m = s_m[t];
        float v0a=0.f,v0b=0.f,v1a=0.f,v1b=0.f,v2a=0.f,v2b=0.f;
        float v3a=0.f,v3b=0.f,v4a=0.f,v4b=0.f;
        const float2* Wsb = (const float2*)(sE1 + 0 * 512);
        const float2* Wab = (const float2*)(sE1 + 1 * 512);
        const float2* W16 = (const float2*)(sE1 + 2 * 512);
        const float2* Wtb = (const float2*)(sE1 + 4 * 512);
        const float2* Wal = (const float2*)(sE1 + 5 * 512);
        #pragma unroll
        for (int c = 0; c < 16; ++c) {
            const float cf0 = m * Y0[c];
            const float cf1 = m * cf0;
            const float cf2 = Y0[c];
            const float cf3 = Z4[c];
            const float cf4 = Z5[c];
            const int idx = c * 16 + y;
            float2 w0 = Wsb[idx]; v0a = fmaf(cf0, w0.x, v0a); v0b = fmaf(cf0, w0.y, v0b);
            float2 w1 = Wab[idx]; v1a = fmaf(cf1, w1.x, v1a); v1b = fmaf(cf1, w1.y, v1b);
            float2 w2 = W16[idx]; v2a = fmaf(cf2, w2.x, v2a); v2b = fmaf(cf2, w2.y, v2b);
            float2 w3 = Wtb[idx]; v3a = fmaf(cf3, w3.x, v3a); v3b = fmaf(cf3, w3.y, v3b);
            float2 w4 = Wal[idx]; v4a = fmaf(cf4, w4.x, v4a); v4b = fmaf(cf4, w4.y, v4b);
        }
        *(float2*)&sV[t][0 * 32 + 2 * y] = make_float2(v0a, v0b);
        *(float2*)&sV[t][1 * 32 + 2 * y] = make_float2(v1a, v1b);
        *(float2*)&sV[t][2 * 32 + 2 * y] = make_float2(v2a, v2b);
        *(float2*)&sV[t][3 * 32 + 2 * y] = make_float2(v3a, v3b);
        *(float2*)&sV[t][4 * 32 + 2 * y] = make_float2(v4a, v4b);
    } else {
        // ---- half B: Z2 + Wt2 scalar-weight matmul, park channel-major ----
        const int w = tid - 256;
        const int t = w >> 4, y = w & 15, x = t;
        float Z2[16];
        #pragma unroll
        for (int c = 0; c < 16; ++c) Z2[c] = 0.f;
        #pragma unroll
        for (int tp = 0; tp < 16; ++tp) {
            const int vm = s_vm[tp];
            const float f2 = (float)((vm >> x) & (vm >> y) & 1);
            #pragma unroll
            for (int c4 = 0; c4 < 4; ++c4) {
                float4 v = *(const float4*)&sX[tp][4 * c4];
                Z2[4*c4+0] = fmaf(f2, v.x, Z2[4*c4+0]);
                Z2[4*c4+1] = fmaf(f2, v.y, Z2[4*c4+1]);
                Z2[4*c4+2] = fmaf(f2, v.z, Z2[4*c4+2]);
                Z2[4*c4+3] = fmaf(f2, v.w, Z2[4*c4+3]);
            }
        }
        float pp[HH];
        #pragma unroll
        for (int h = 0; h < HH; ++h) pp[h] = 0.f;
        // Wt2 = 16*W1[2*512+..]; fold the pow2 into the coefficient (exact).
        MM_SL(W1 + 2 * 512, 2, 16.f * Z2[ci], pp);
        // park: cell keyed as (y_out*16 + x_out) = (y*16 + t) so reader
        // (q,p) hits (q*16+p).
        const int cell = y * 16 + t;
        #pragma unroll
        for (int h4 = 0; h4 < 8; ++h4)
            *(float4*)&sPP2[(h4 * 256 + cell) * 4] =
                make_float4(pp[4*h4], pp[4*h4+1], pp[4*h4+2], pp[4*h4+3]);
    }
    __syncthreads();  // B3 (sV + sPP2 + s_P ready) — final barrier

    if (tid < 256) {
        // output thread (q,p) computes cell (x=p, y=q) and stores directly:
        // chunk (i*16+q)*128 + h4*16 + p  -> p lane-varying, 256 B coalesced.
        const int q = tid >> 4, p = tid & 15;
        const float vy  = (s_P[p][q] >= 0) ? 1.f : 0.f;
        const float dxy = (p == q) ? 1.f : 0.f;
        float4* F4 = (float4*)F1c;
        const size_t basec = ((size_t)i * 16 + q) * 128 + p;
        #pragma unroll
        for (int h4 = 0; h4 < 8; ++h4) {
            const float4 V0 = *(const float4*)&sV[p][0 * 32 + 4 * h4];
            const float4 V1 = *(const float4*)&sV[p][1 * 32 + 4 * h4];
            const float4 V2 = *(const float4*)&sV[p][2 * 32 + 4 * h4];
            const float4 V3 = *(const float4*)&sV[p][3 * 32 + 4 * h4];
            const float4 V4 = *(const float4*)&sV[p][4 * 32 + 4 * h4];
            const float4 PP = *(const float4*)&sPP2[(h4 * 256 + q * 16 + p) * 4];
            float a_ = vy*(V0.x+V2.x) + V1.x + V3.x + dxy*V4.x + PP.x + bias[4*h4+0];
            float b_ = vy*(V0.y+V2.y) + V1.y + V3.y + dxy*V4.y + PP.y + bias[4*h4+1];
            float c_ = vy*(V0.z+V2.z) + V1.z + V3.z + dxy*V4.z + PP.z + bias[4*h4+2];
            float d_ = vy*(V0.w+V2.w) + V1.w + V3.w + dxy*V4.w + PP.w + bias[4*h4+3];
            F4[basec + h4 * 16] = make_float4(a_ > 0.f ? a_ : 0.f, b_ > 0.f ? b_ : 0.f,
                                              c_ > 0.f ? c_ : 0.f, d_ > 0.f ? d_ : 0.f);
        }
    }
}

// ---------------- layer 2 ----------------
// Effective slices: Wsb = precomputed Wsb2 (global, from l1); W16 = W2+15*1024
// (direct); Wt2 = 16*(W2+2*1024) (fold 16 into cf); Wab/Wtb/Wal = direct W2
// slices copied verbatim to LDS for the lane-varying epilogue reads.
// F1c chunk (j*16+q)*128 + c4*16 + p = channels 4c4..4c4+3 of F1[j][p][q][:].
__global__ __launch_bounds__(512)
void ccn_l2(const float* __restrict__ F1c, const int* __restrict__ nbrs,
            const float* __restrict__ W2, const float* __restrict__ bias,
            const float* __restrict__ fcw, const float* __restrict__ fcb,
            float* __restrict__ out, const float* __restrict__ Wsb2)
{
    __shared__ float sW3[3 * 1024];    // 12 KB: 0:Wab 1:Wtb 2:Wal (verbatim)
    __shared__ float sRpp[256 * 36];   // 36 KB: R rows, then half-B pp results
    __shared__ float s_stb[16 * 33];
    __shared__ float s_sall[C2];
    __shared__ int   s_nbi[16];
    __shared__ int   s_PQ[16 * 17];    // nbj, then overwritten with P (wave-local)
    __shared__ float s_red[4];

    const int tid  = threadIdx.x;
    const int i    = ((blockIdx.x & 7) << 5) | (blockIdx.x >> 3);  // XCD swizzle
    const int lane = tid & 63;
    const float4* F4 = (const float4*)F1c;

    if (tid < 16) s_nbi[tid] = nbrs[i * 16 + tid];
    __syncthreads();  // B0

    if (tid < 256) {
        const int t = tid >> 4, y = tid & 15;
        const int j = s_nbi[t];
        s_PQ[t * 17 + y] = nbrs[j * 16 + y];
    } else {
        const int w = tid - 256;
        #pragma unroll
        for (int s = 0; s < 4; ++s) {
            const int u = w + s * 256;
            sW3[u]        = W2[1 * 1024 + u];   // Wab
            sW3[1024 + u] = W2[3 * 1024 + u];   // Wtb
            sW3[2048 + u] = W2[4 * 1024 + u];   // Wal
        }
    }
    __syncthreads();  // B1

    if (tid < 256) {
        const int t = tid >> 4, y = tid & 15;
        const int tgt = s_nbi[y];
        int p = -1;
        #pragma unroll
        for (int q = 0; q < 16; ++q) if (s_PQ[t * 17 + q] == tgt) p = q;
        s_PQ[t * 17 + y] = p;   // overwrite: reads above precede write (wave lockstep)
    }
    __syncthreads();  // B2

    float pre[HH];
    float sab[C2];
    float pp[HH];

    if (tid < 256) {
        // ---- half A: R gather + Wsb/W16 scalar-weight matmuls ----
        const int t = tid >> 4, y = tid & 15;
        const int j = s_nbi[t];
        const int p = s_PQ[t * 17 + y];
        const float mp = (p >= 0) ? 1.f : 0.f;
        const int pc = p >= 0 ? p : 0;
        const size_t jbase = (size_t)j * 2048;   // 16*128 chunks per tile

        float R[C2];
        #pragma unroll
        for (int c = 0; c < C2; ++c) R[c] = 0.f;
        #pragma unroll
        for (int b = 0; b < 16; ++b) {
            const int q = s_PQ[t * 17 + b];
            const float mm = (q >= 0) ? mp : 0.f;
            const int qc = q >= 0 ? q : 0;
            const size_t rb = jbase + (size_t)qc * 128 + pc;
            #pragma unroll
            for (int c4 = 0; c4 < 8; ++c4) {
                float4 v = F4[rb + c4 * 16];
                R[4*c4+0] = fmaf(mm, v.x, R[4*c4+0]);
                R[4*c4+1] = fmaf(mm, v.y, R[4*c4+1]);
                R[4*c4+2] = fmaf(mm, v.z, R[4*c4+2]);
                R[4*c4+3] = fmaf(mm, v.w, R[4*c4+3]);
            }
        }
        #pragma unroll
        for (int c4 = 0; c4 < 8; ++c4)
            *(float4*)&sRpp[(t * 16 + y) * 36 + 4 * c4] =
                make_float4(R[4*c4+0], R[4*c4+1], R[4*c4+2], R[4*c4+3]);

        #pragma unroll
        for (int h = 0; h < HH; ++h) pre[h] = 0.f;
        MM_SL(Wsb2, 4, R[ci], pre);                    // Wsb^T R

        #pragma unroll
        for (int c = 0; c < C2; ++c) {
            float s = R[c];
            s += __shfl_xor(s, 1);
            s += __shfl_xor(s, 2);
            s += __shfl_xor(s, 4);
            s += __shfl_xor(s, 8);
            sab[c] = s;
        }

        float D[C2];
        {
            const size_t db = jbase + (size_t)pc * 128 + pc;
            #pragma unroll
            for (int c4 = 0; c4 < 8; ++c4) {
                float4 v = F4[db + c4 * 16];
                D[4*c4+0] = mp * v.x; D[4*c4+1] = mp * v.y;
                D[4*c4+2] = mp * v.z; D[4*c4+3] = mp * v.w;
            }
        }
        MM_SL(W2 + 15 * 1024, 4, D[ci], pre);          // W16^T D (direct slice)
    } else {
        // ---- half B: ST gather + Wt2 scalar-weight matmul ----
        const int w = tid - 256;
        const int g = w >> 4, l = w & 15;              // output (x=l, y=g)
        float ST[C2];
        #pragma unroll
        for (int c = 0; c < C2; ++c) ST[c] = 0.f;
        #pragma unroll
        for (int tp = 0; tp < 16; ++tp) {
            const int jt = s_nbi[tp];
            const int py = s_PQ[tp * 17 + g];          // group-uniform
            const int px = s_PQ[tp * 17 + l];          // lane-varying
            const float mm = (px >= 0 && py >= 0) ? 1.f : 0.f;
            const int pyc = py >= 0 ? py : 0;
            const int pxc = px >= 0 ? px : 0;
            const size_t rb = (size_t)jt * 2048 + (size_t)pyc * 128 + pxc;
            #pragma unroll
            for (int c4 = 0; c4 < 8; ++c4) {
                float4 v = F4[rb + c4 * 16];
                ST[4*c4+0] = fmaf(mm, v.x, ST[4*c4+0]);
                ST[4*c4+1] = fmaf(mm, v.y, ST[4*c4+1]);
                ST[4*c4+2] = fmaf(mm, v.z, ST[4*c4+2]);
                ST[4*c4+3] = fmaf(mm, v.w, ST[4*c4+3]);
            }
        }
        #pragma unroll
        for (int h = 0; h < HH; ++h) pp[h] = 0.f;
        // Wt2 = 16*(W2+2*1024); fold the pow2 into the coefficient (exact).
        MM_SL(W2 + 2 * 1024, 4, 16.f * ST[ci], pp);    // Wt2^T ST
    }
    __syncthreads();  // B3  (sR rows complete)

    if (tid < 256) {
        // stb[x2][c] = sum_t R[t][x2][c]
        #pragma unroll
        for (int k = 0; k < 2; ++k) {
            const int x2 = (tid >> 5) + 8 * k;
            const int c = tid & 31;
            float s = 0.f;
            #pragma unroll
            for (int tt = 0; tt < 16; ++tt) s += sRpp[(tt * 16 + x2) * 36 + c];
            s_stb[x2 * 33 + c] = s;
        }
    }
    __syncthreads();  // B4  (stb complete; sR now dead)

    if (tid < 256) {
        if (tid < 32) {
            float s = 0.f;
            #pragma unroll
            for (int x2 = 0; x2 < 16; ++x2) s += s_stb[x2 * 33 + tid];
            s_sall[tid] = s;
        }
    } else {
        // half B parks its pp into the dead sR buffer at row x*16+y = l*16+g
        const int w = tid - 256;
        const int g = w >> 4, l = w & 15;
        float* dst = &sRpp[(l * 16 + g) * 36];
        #pragma unroll
        for (int h4 = 0; h4 < 8; ++h4)
            *(float4*)&dst[4 * h4] = make_float4(pp[4*h4], pp[4*h4+1], pp[4*h4+2], pp[4*h4+3]);
    }
    __syncthreads();  // B5

    if (tid < 256) {
        const int t = tid >> 4, y = tid & 15, x = t;
        const float dxy = (x == y) ? 1.f : 0.f;
        // cooperative matvecs Wab/Wtb/Wal (lane y -> h=2y,2y+1), combine via shfl
        float S0 = 0.f, S1 = 0.f, L0 = 0.f, L1 = 0.f;
        {
            const float2* Wab = (const float2*)(sW3 + 0 * 1024);
            const float2* Wtb = (const float2*)(sW3 + 1 * 1024);
            const float2* Wal = (const float2*)(sW3 + 2 * 1024);
            #pragma unroll
            for (int c = 0; c < C2; ++c) {
                const float cfa = sab[c];
                const float cft = s_stb[t * 33 + c];
                const float cfl = s_sall[c];
                const int idx = c * 16 + y;
                float2 wa = Wab[idx]; S0 = fmaf(cfa, wa.x, S0); S1 = fmaf(cfa, wa.y, S1);
                float2 wt = Wtb[idx]; S0 = fmaf(cft, wt.x, S0); S1 = fmaf(cft, wt.y, S1);
                float2 wl = Wal[idx]; L0 = fmaf(cfl, wl.x, L0); L1 = fmaf(cfl, wl.y, L1);
            }
        }
        const int gbase = (t & 3) * 16;
        #pragma unroll
        for (int h = 0; h < HH; ++h) {
            const int src = gbase + (h >> 1);
            const float sv = (h & 1) ? S1 : S0;
            const float lv = (h & 1) ? L1 : L0;
            pre[h] += __shfl(sv, src, 64) + dxy * __shfl(lv, src, 64);
        }
        // pick up half B's Wt2 contribution (row t*16+y)
        {
            const float* ppr = &sRpp[(t * 16 + y) * 36];
            #pragma unroll
            for (int h4 = 0; h4 < 8; ++h4) {
                const float4 v = *(const float4*)&ppr[4 * h4];
                pre[4*h4+0] += v.x; pre[4*h4+1] += v.y;
                pre[4*h4+2] += v.z; pre[4*h4+3] += v.w;
            }
        }
        // epilogue: bias, relu, dot fcw, wave reduce
        float local = 0.f;
        #pragma unroll
        for (int h = 0; h < HH; ++h) {
            float v = pre[h] + bias[h];
            v = v > 0.f ? v : 0.f;
            local += v * fcw[h];
        }
        #pragma unroll
        for (int off = 32; off > 0; off >>= 1) local += __shfl_down(local, off, 64);
        if (lane == 0) s_red[tid >> 6] = local;
    }
    __syncthreads();  // B6
    if (tid == 0) {
        const float v = s_red[0] + s_red[1] + s_red[2] + s_red[3]
                      + fcb[0] * (1.f / 256.f);
        atomicAdd(out, v);
    }
}

extern "C" void kernel_launch(void* const* d_in, const int* in_sizes, int n_in,
                              void* d_out, int out_size, void* d_ws, size_t ws_size,
                              hipStream_t stream) {
    const float* X    = (const float*)d_in[0];
    const int*   nbrs = (const int*)  d_in[1];
    const float* W1   = (const float*)d_in[2];
    const float* b1   = (const float*)d_in[3];
    const float* W2   = (const float*)d_in[4];
    const float* b2   = (const float*)d_in[5];
    const float* fc_w = (const float*)d_in[6];
    const float* fc_b = (const float*)d_in[7];
    float* outp = (float*)d_out;

    float* F1c  = (float*)d_ws;          // 256*16*16*32 floats = 8 MB
    float* Wsb2 = F1c + 2097152;         // 1024 floats, written by l1 blocks 0,1

    ccn_l1<<<NV, 512, 0, stream>>>(X, nbrs, W1, b1, F1c, outp, W2, Wsb2);
    ccn_l2<<<NV, 512, 0, stream>>>(F1c, nbrs, W2, b2, fc_w, fc_b, outp, Wsb2);
}

// Round 2
// 106.156 us; speedup vs baseline: 1.0698x; 1.0698x over previous
//
#include <hip/hip_runtime.h>

// CCN_2D on MI355X. N=256 vertices, K=16, C0=16, H=32.
// Facts (validated by exact passes R1-R10):
//  * CH rows one-hot => T_t[a][b][c] = Fin[j_t, P_t[a], P_t[b], c].
//  * A = I_16 collapses contract18 to 6 effective weight matrices.
//  * P_t[t] = -1 (no self-loops) => c17 / d_ttt terms vanish.
//  * Layer-1 input is broadcast of X => rank-1 closed form, no gathers.
//  * F1 channel-interleaved: chunk (i*16+q)*128 + c4*16 + p holds channels
//    4c4..4c4+3 of F1[i][p][q][:] (16 B stride on lane-varying p).
// Structure ladder (measured): 2 plain launches (R6, 107.7) beats 3 launches
// (113.9), coop launch (154.5), and 1 launch w/ device-scope flags (122.4).
// Measured window = 2x ~43.2us harness ws-poison fills (untouchable) + ~20us
// of kernels. Kernels are VALU-issue-bound (1 block/CU, 2 waves/SIMD).
// R1 post-mortem: wave-uniform "scalar pipe" weight loads (MM_SL) regressed
// +7.3us — 1024-float weight matrices cannot live in SGPRs, so the compiler
// serialized the fma chain on load latency. MM_RL (one coalesced float4/lane
// load -> distributed VGPRs -> readlane broadcast) has zero in-loop latency.
// This round: MM_RL restored, but its one-time weight load points DIRECTLY
// at global (W1/W2 verbatim slices; x16 on Wt2 folded into the coefficient,
// bit-exact; Wsb2 precomputed into ws by l1 blocks 0-1). l2's 6-slice E2 LDS
// preprocessing is deleted except a verbatim 12 KB copy of the 3 epilogue
// slices (lane-varying float2 reads keep those in LDS).

constexpr int KN = 16, HH = 32, NV = 256, C2 = 32;

__device__ __forceinline__ float rlane(float v, int l) {
    return __int_as_float(__builtin_amdgcn_readlane(__float_as_int(v), l));
}

// ACC[h] += COEF(ci) * W[ci][h], ci in [0, 8*NB), W row-major [c][32]
// (global or LDS). Wave-coalesced weight load (float4/lane) + readlane
// broadcast. All 64 lanes of the executing wave must be active.
#define MM_RL(WPTR, NB, COEF_EXPR, ACC) do {                                   \
    _Pragma("unroll")                                                          \
    for (int B = 0; B < (NB); ++B) {                                           \
        const float4 w_ = ((const float4*)(WPTR))[B * 64 + lane];              \
        _Pragma("unroll")                                                      \
        for (int cc = 0; cc < 8; ++cc) {                                       \
            const int ci = B * 8 + cc;                                         \
            const float cf_ = (COEF_EXPR);                                     \
            _Pragma("unroll")                                                  \
            for (int h4 = 0; h4 < 8; ++h4) {                                   \
                const int src_ = 8 * cc + h4;                                  \
                (ACC)[4*h4+0] = fmaf(cf_, rlane(w_.x, src_), (ACC)[4*h4+0]);   \
                (ACC)[4*h4+1] = fmaf(cf_, rlane(w_.y, src_), (ACC)[4*h4+1]);   \
                (ACC)[4*h4+2] = fmaf(cf_, rlane(w_.z, src_), (ACC)[4*h4+2]);   \
                (ACC)[4*h4+3] = fmaf(cf_, rlane(w_.w, src_), (ACC)[4*h4+3]);   \
            }                                                                  \
        }                                                                      \
    }                                                                          \
} while (0)

// ---------------- layer 1 ----------------
// E1 slices (512 floats each): 0:Wsb 1:Wab 2:W16 3:(dead) 4:Wtb 5:Wal
// pre = vy*(m*Y0.Wsb) + (m^2*Y0).Wab + vy*(Y0.W16) + Z2.Wt2 + Z4.Wtb + dxy*Z5.Wal
// Wt2 = 16*W1[2*512+..] applied via MM_RL on W1 directly with cf = 16*Z2.
// Output layout (float4 chunks): F1c chunk index = (i*16+q)*128 + c4*16 + p,
// holding channels c4*4..c4*4+3 of logical F1[i][p][q][:]. (q,p) = (y,x).
__global__ __launch_bounds__(512)
void ccn_l1(const float* __restrict__ X, const int* __restrict__ nbrs,
            const float* __restrict__ W1, const float* __restrict__ bias,
            float* __restrict__ F1c, float* __restrict__ outz,
            const float* __restrict__ W2f, float* __restrict__ Wsb2)
{
    __shared__ float sE1[6 * 512];       // 12 KB
    __shared__ float sPP2[8 * 256 * 4];  // 32 KB, channel-major [h4][cell][4]
    __shared__ float sX[16][20];
    __shared__ float sV[16][164];        // 5 matvec results x 32 per group
    __shared__ int   s_nbi[16];
    __shared__ int   s_nbj[16][17];
    __shared__ int   s_P[16][16];
    __shared__ int   s_vm[16];
    __shared__ float s_m[16];

    const int tid  = threadIdx.x;
    const int i    = ((blockIdx.x & 7) << 5) | (blockIdx.x >> 3);  // XCD swizzle
    const int lane = tid & 63;

    if (blockIdx.x == 0 && tid == 0) outz[0] = 0.f;   // zero accumulator for l2

    // blocks 0,1: precompute the one combined layer-2 slice Wsb2 (1024 floats)
    // into the workspace so l2 can skip its E2 preprocessing. Bit-exact vs the
    // old in-l2 sE2[u] expression.
    if (blockIdx.x < 2) {
        const int u = (blockIdx.x << 9) | tid;
        float acc = 0.f;
        #pragma unroll
        for (int g = 6; g < 15; ++g) acc += W2f[g * 1024 + u];
        Wsb2[u] = 16.f * W2f[u] + W2f[5 * 1024 + u] + 16.f * acc;
    }

    if (tid < 16) s_nbi[tid] = nbrs[i * 16 + tid];
    __syncthreads();  // B0

    if (tid < 256) {
        const int t = tid >> 4, y = tid & 15;
        const int j = s_nbi[t];
        s_nbj[t][y] = nbrs[j * 16 + y];
        sX[t][y]    = X[j * 16 + y];
    } else {
        const int u = tid - 256;       // E1 entries 0..255
        float acc = 0.f;
        #pragma unroll
        for (int g = 6; g < 15; ++g) acc += W1[g * 512 + u];
        sE1[u]        = 16.f * W1[u] + W1[5 * 512 + u] + 16.f * acc;
        sE1[512 + u]  = W1[512 + u];
        sE1[1024 + u] = W1[15 * 512 + u];
        sE1[2048 + u] = W1[3 * 512 + u];
        sE1[2560 + u] = W1[4 * 512 + u];
    }
    __syncthreads();  // B1

    if (tid < 256) {
        const int t = tid >> 4, y = tid & 15;
        const int tgt = s_nbi[y];
        int p = -1;
        #pragma unroll
        for (int q = 0; q < 16; ++q) if (s_nbj[t][q] == tgt) p = q;
        s_P[t][y] = p;
        unsigned long long bal = __ballot(p >= 0);
        if (y == 0) {
            int vm = (int)((bal >> ((t & 3) * 16)) & 0xFFFFull);
            s_vm[t] = vm;
            s_m[t]  = (float)__popc(vm);
        }
    } else {
        const int u = tid;             // E1 entries 256..511
        float acc = 0.f;
        #pragma unroll
        for (int g = 6; g < 15; ++g) acc += W1[g * 512 + u];
        sE1[u]        = 16.f * W1[u] + W1[5 * 512 + u] + 16.f * acc;
        sE1[512 + u]  = W1[512 + u];
        sE1[1024 + u] = W1[15 * 512 + u];
        sE1[2048 + u] = W1[3 * 512 + u];
        sE1[2560 + u] = W1[4 * 512 + u];
    }
    __syncthreads();  // B2

    if (tid < 256) {
        // ---- half A: Z4/Z5 + 5 cooperative matvecs (lane y -> h=2y,2y+1) ----
        const int t = tid >> 4, y = tid & 15, x = t;
        float Y0[16];
        #pragma unroll
        for (int c4 = 0; c4 < 4; ++c4) {
            float4 v = *(const float4*)&sX[t][4 * c4];
            Y0[4*c4+0] = v.x; Y0[4*c4+1] = v.y; Y0[4*c4+2] = v.z; Y0[4*c4+3] = v.w;
        }
        float Z4[16], Z5[16];
        #pragma unroll
        for (int c = 0; c < 16; ++c) { Z4[c] = 0.f; Z5[c] = 0.f; }
        #pragma unroll
        for (int tp = 0; tp < 16; ++tp) {
            const int vm = s_vm[tp];
            const float mt = s_m[tp];
            const float fb = ((vm >> x) & 1) ? mt : 0.f;
            const float f5 = mt * mt;
            #pragma unroll
            for (int c4 = 0; c4 < 4; ++c4) {
                float4 v = *(const float4*)&sX[tp][4 * c4];
                Z4[4*c4+0] = fmaf(fb, v.x, Z4[4*c4+0]);
                Z4[4*c4+1] = fmaf(fb, v.y, Z4[4*c4+1]);
                Z4[4*c4+2] = fmaf(fb, v.z, Z4[4*c4+2]);
                Z4[4*c4+3] = fmaf(fb, v.w, Z4[4*c4+3]);
                Z5[4*c4+0] = fmaf(f5, v.x, Z5[4*c4+0]);
                Z5[4*c4+1] = fmaf(f5, v.y, Z5[4*c4+1]);
                Z5[4*c4+2] = fmaf(f5, v.z, Z5[4*c4+2]);
                Z5[4*c4+3] = fmaf(f5, v.w, Z5[4*c4+3]);
            }
        }
        const float m = s_m[t];
        float v0a=0.f,v0b=0.f,v1a=0.f,v1b=0.f,v2a=0.f,v2b=0.f;
        float v3a=0.f,v3b=0.f,v4a=0.f,v4b=0.f;
        const float2* Wsb = (const float2*)(sE1 + 0 * 512);
        const float2* Wab = (const float2*)(sE1 + 1 * 512);
        const float2* W16 = (const float2*)(sE1 + 2 * 512);
        const float2* Wtb = (const float2*)(sE1 + 4 * 512);
        const float2* Wal = (const float2*)(sE1 + 5 * 512);
        #pragma unroll
        for (int c = 0; c < 16; ++c) {
            const float cf0 = m * Y0[c];
            const float cf1 = m * cf0;
            const float cf2 = Y0[c];
            const float cf3 = Z4[c];
            const float cf4 = Z5[c];
            const int idx = c * 16 + y;
            float2 w0 = Wsb[idx]; v0a = fmaf(cf0, w0.x, v0a); v0b = fmaf(cf0, w0.y, v0b);
            float2 w1 = Wab[idx]; v1a = fmaf(cf1, w1.x, v1a); v1b = fmaf(cf1, w1.y, v1b);
            float2 w2 = W16[idx]; v2a = fmaf(cf2, w2.x, v2a); v2b = fmaf(cf2, w2.y, v2b);
            float2 w3 = Wtb[idx]; v3a = fmaf(cf3, w3.x, v3a); v3b = fmaf(cf3, w3.y, v3b);
            float2 w4 = Wal[idx]; v4a = fmaf(cf4, w4.x, v4a); v4b = fmaf(cf4, w4.y, v4b);
        }
        *(float2*)&sV[t][0 * 32 + 2 * y] = make_float2(v0a, v0b);
        *(float2*)&sV[t][1 * 32 + 2 * y] = make_float2(v1a, v1b);
        *(float2*)&sV[t][2 * 32 + 2 * y] = make_float2(v2a, v2b);
        *(float2*)&sV[t][3 * 32 + 2 * y] = make_float2(v3a, v3b);
        *(float2*)&sV[t][4 * 32 + 2 * y] = make_float2(v4a, v4b);
    } else {
        // ---- half B: Z2 + Wt2 readlane-matmul (weights direct from global),
        //      park channel-major ----
        const int w = tid - 256;
        const int t = w >> 4, y = w & 15, x = t;
        float Z2[16];
        #pragma unroll
        for (int c = 0; c < 16; ++c) Z2[c] = 0.f;
        #pragma unroll
        for (int tp = 0; tp < 16; ++tp) {
            const int vm = s_vm[tp];
            const float f2 = (float)((vm >> x) & (vm >> y) & 1);
            #pragma unroll
            for (int c4 = 0; c4 < 4; ++c4) {
                float4 v = *(const float4*)&sX[tp][4 * c4];
                Z2[4*c4+0] = fmaf(f2, v.x, Z2[4*c4+0]);
                Z2[4*c4+1] = fmaf(f2, v.y, Z2[4*c4+1]);
                Z2[4*c4+2] = fmaf(f2, v.z, Z2[4*c4+2]);
                Z2[4*c4+3] = fmaf(f2, v.w, Z2[4*c4+3]);
            }
        }
        float pp[HH];
        #pragma unroll
        for (int h = 0; h < HH; ++h) pp[h] = 0.f;
        // Wt2 = 16*W1[2*512+..]; fold the pow2 into the coefficient (exact).
        MM_RL(W1 + 2 * 512, 2, 16.f * Z2[ci], pp);
        // park: cell keyed as (y_out*16 + x_out) = (y*16 + t) so reader
        // (q,p) hits (q*16+p).
        const int cell = y * 16 + t;
        #pragma unroll
        for (int h4 = 0; h4 < 8; ++h4)
            *(float4*)&sPP2[(h4 * 256 + cell) * 4] =
                make_float4(pp[4*h4], pp[4*h4+1], pp[4*h4+2], pp[4*h4+3]);
    }
    __syncthreads();  // B3 (sV + sPP2 + s_P ready) — final barrier

    if (tid < 256) {
        // output thread (q,p) computes cell (x=p, y=q) and stores directly:
        // chunk (i*16+q)*128 + h4*16 + p  -> p lane-varying, 256 B coalesced.
        const int q = tid >> 4, p = tid & 15;
        const float vy  = (s_P[p][q] >= 0) ? 1.f : 0.f;
        const float dxy = (p == q) ? 1.f : 0.f;
        float4* F4 = (float4*)F1c;
        const size_t basec = ((size_t)i * 16 + q) * 128 + p;
        #pragma unroll
        for (int h4 = 0; h4 < 8; ++h4) {
            const float4 V0 = *(const float4*)&sV[p][0 * 32 + 4 * h4];
            const float4 V1 = *(const float4*)&sV[p][1 * 32 + 4 * h4];
            const float4 V2 = *(const float4*)&sV[p][2 * 32 + 4 * h4];
            const float4 V3 = *(const float4*)&sV[p][3 * 32 + 4 * h4];
            const float4 V4 = *(const float4*)&sV[p][4 * 32 + 4 * h4];
            const float4 PP = *(const float4*)&sPP2[(h4 * 256 + q * 16 + p) * 4];
            float a_ = vy*(V0.x+V2.x) + V1.x + V3.x + dxy*V4.x + PP.x + bias[4*h4+0];
            float b_ = vy*(V0.y+V2.y) + V1.y + V3.y + dxy*V4.y + PP.y + bias[4*h4+1];
            float c_ = vy*(V0.z+V2.z) + V1.z + V3.z + dxy*V4.z + PP.z + bias[4*h4+2];
            float d_ = vy*(V0.w+V2.w) + V1.w + V3.w + dxy*V4.w + PP.w + bias[4*h4+3];
            F4[basec + h4 * 16] = make_float4(a_ > 0.f ? a_ : 0.f, b_ > 0.f ? b_ : 0.f,
                                              c_ > 0.f ? c_ : 0.f, d_ > 0.f ? d_ : 0.f);
        }
    }
}

// ---------------- layer 2 ----------------
// Effective slices: Wsb = precomputed Wsb2 (global, from l1); W16 = W2+15*1024
// (direct global); Wt2 = 16*(W2+2*1024) (fold 16 into cf); Wab/Wtb/Wal =
// verbatim W2 slices copied to LDS for the lane-varying epilogue reads.
// F1c chunk (j*16+q)*128 + c4*16 + p = channels 4c4..4c4+3 of F1[j][p][q][:].
__global__ __launch_bounds__(512)
void ccn_l2(const float* __restrict__ F1c, const int* __restrict__ nbrs,
            const float* __restrict__ W2, const float* __restrict__ bias,
            const float* __restrict__ fcw, const float* __restrict__ fcb,
            float* __restrict__ out, const float* __restrict__ Wsb2)
{
    __shared__ float sW3[3 * 1024];    // 12 KB: 0:Wab 1:Wtb 2:Wal (verbatim)
    __shared__ float sRpp[256 * 36];   // 36 KB: R rows, then half-B pp results
    __shared__ float s_stb[16 * 33];
    __shared__ float s_sall[C2];
    __shared__ int   s_nbi[16];
    __shared__ int   s_PQ[16 * 17];    // nbj, then overwritten with P (wave-local)
    __shared__ float s_red[4];

    const int tid  = threadIdx.x;
    const int i    = ((blockIdx.x & 7) << 5) | (blockIdx.x >> 3);  // XCD swizzle
    const int lane = tid & 63;
    const float4* F4 = (const float4*)F1c;

    if (tid < 16) s_nbi[tid] = nbrs[i * 16 + tid];
    __syncthreads();  // B0

    if (tid < 256) {
        const int t = tid >> 4, y = tid & 15;
        const int j = s_nbi[t];
        s_PQ[t * 17 + y] = nbrs[j * 16 + y];
    } else {
        const int w = tid - 256;
        #pragma unroll
        for (int s = 0; s < 4; ++s) {
            const int u = w + s * 256;
            sW3[u]        = W2[1 * 1024 + u];   // Wab
            sW3[1024 + u] = W2[3 * 1024 + u];   // Wtb
            sW3[2048 + u] = W2[4 * 1024 + u];   // Wal
        }
    }
    __syncthreads();  // B1

    if (tid < 256) {
        const int t = tid >> 4, y = tid & 15;
        const int tgt = s_nbi[y];
        int p = -1;
        #pragma unroll
        for (int q = 0; q < 16; ++q) if (s_PQ[t * 17 + q] == tgt) p = q;
        s_PQ[t * 17 + y] = p;   // overwrite: reads above precede write (wave lockstep)
    }
    __syncthreads();  // B2

    float pre[HH];
    float sab[C2];
    float pp[HH];

    if (tid < 256) {
        // ---- half A: R gather + Wsb/W16 readlane matmuls (global weights) ----
        const int t = tid >> 4, y = tid & 15;
        const int j = s_nbi[t];
        const int p = s_PQ[t * 17 + y];
        const float mp = (p >= 0) ? 1.f : 0.f;
        const int pc = p >= 0 ? p : 0;
        const size_t jbase = (size_t)j * 2048;   // 16*128 chunks per tile

        float R[C2];
        #pragma unroll
        for (int c = 0; c < C2; ++c) R[c] = 0.f;
        #pragma unroll
        for (int b = 0; b < 16; ++b) {
            const int q = s_PQ[t * 17 + b];
            const float mm = (q >= 0) ? mp : 0.f;
            const int qc = q >= 0 ? q : 0;
            const size_t rb = jbase + (size_t)qc * 128 + pc;
            #pragma unroll
            for (int c4 = 0; c4 < 8; ++c4) {
                float4 v = F4[rb + c4 * 16];
                R[4*c4+0] = fmaf(mm, v.x, R[4*c4+0]);
                R[4*c4+1] = fmaf(mm, v.y, R[4*c4+1]);
                R[4*c4+2] = fmaf(mm, v.z, R[4*c4+2]);
                R[4*c4+3] = fmaf(mm, v.w, R[4*c4+3]);
            }
        }
        #pragma unroll
        for (int c4 = 0; c4 < 8; ++c4)
            *(float4*)&sRpp[(t * 16 + y) * 36 + 4 * c4] =
                make_float4(R[4*c4+0], R[4*c4+1], R[4*c4+2], R[4*c4+3]);

        #pragma unroll
        for (int h = 0; h < HH; ++h) pre[h] = 0.f;
        MM_RL(Wsb2, 4, R[ci], pre);                    // Wsb^T R

        #pragma unroll
        for (int c = 0; c < C2; ++c) {
            float s = R[c];
            s += __shfl_xor(s, 1);
            s += __shfl_xor(s, 2);
            s += __shfl_xor(s, 4);
            s += __shfl_xor(s, 8);
            sab[c] = s;
        }

        float D[C2];
        {
            const size_t db = jbase + (size_t)pc * 128 + pc;
            #pragma unroll
            for (int c4 = 0; c4 < 8; ++c4) {
                float4 v = F4[db + c4 * 16];
                D[4*c4+0] = mp * v.x; D[4*c4+1] = mp * v.y;
                D[4*c4+2] = mp * v.z; D[4*c4+3] = mp * v.w;
            }
        }
        MM_RL(W2 + 15 * 1024, 4, D[ci], pre);          // W16^T D (direct slice)
    } else {
        // ---- half B: ST gather + Wt2 readlane matmul (global weights) ----
        const int w = tid - 256;
        const int g = w >> 4, l = w & 15;              // output (x=l, y=g)
        float ST[C2];
        #pragma unroll
        for (int c = 0; c < C2; ++c) ST[c] = 0.f;
        #pragma unroll
        for (int tp = 0; tp < 16; ++tp) {
            const int jt = s_nbi[tp];
            const int py = s_PQ[tp * 17 + g];          // group-uniform
            const int px = s_PQ[tp * 17 + l];          // lane-varying
            const float mm = (px >= 0 && py >= 0) ? 1.f : 0.f;
            const int pyc = py >= 0 ? py : 0;
            const int pxc = px >= 0 ? px : 0;
            const size_t rb = (size_t)jt * 2048 + (size_t)pyc * 128 + pxc;
            #pragma unroll
            for (int c4 = 0; c4 < 8; ++c4) {
                float4 v = F4[rb + c4 * 16];
                ST[4*c4+0] = fmaf(mm, v.x, ST[4*c4+0]);
                ST[4*c4+1] = fmaf(mm, v.y, ST[4*c4+1]);
                ST[4*c4+2] = fmaf(mm, v.z, ST[4*c4+2]);
                ST[4*c4+3] = fmaf(mm, v.w, ST[4*c4+3]);
            }
        }
        #pragma unroll
        for (int h = 0; h < HH; ++h) pp[h] = 0.f;
        // Wt2 = 16*(W2+2*1024); fold the pow2 into the coefficient (exact).
        MM_RL(W2 + 2 * 1024, 4, 16.f * ST[ci], pp);    // Wt2^T ST
    }
    __syncthreads();  // B3  (sR rows complete)

    if (tid < 256) {
        // stb[x2][c] = sum_t R[t][x2][c]
        #pragma unroll
        for (int k = 0; k < 2; ++k) {
            const int x2 = (tid >> 5) + 8 * k;
            const int c = tid & 31;
            float s = 0.f;
            #pragma unroll
            for (int tt = 0; tt < 16; ++tt) s += sRpp[(tt * 16 + x2) * 36 + c];
            s_stb[x2 * 33 + c] = s;
        }
    }
    __syncthreads();  // B4  (stb complete; sR now dead)

    if (tid < 256) {
        if (tid < 32) {
            float s = 0.f;
            #pragma unroll
            for (int x2 = 0; x2 < 16; ++x2) s += s_stb[x2 * 33 + tid];
            s_sall[tid] = s;
        }
    } else {
        // half B parks its pp into the dead sR buffer at row x*16+y = l*16+g
        const int w = tid - 256;
        const int g = w >> 4, l = w & 15;
        float* dst = &sRpp[(l * 16 + g) * 36];
        #pragma unroll
        for (int h4 = 0; h4 < 8; ++h4)
            *(float4*)&dst[4 * h4] = make_float4(pp[4*h4], pp[4*h4+1], pp[4*h4+2], pp[4*h4+3]);
    }
    __syncthreads();  // B5

    if (tid < 256) {
        const int t = tid >> 4, y = tid & 15, x = t;
        const float dxy = (x == y) ? 1.f : 0.f;
        // cooperative matvecs Wab/Wtb/Wal (lane y -> h=2y,2y+1), combine via shfl
        float S0 = 0.f, S1 = 0.f, L0 = 0.f, L1 = 0.f;
        {
            const float2* Wab = (const float2*)(sW3 + 0 * 1024);
            const float2* Wtb = (const float2*)(sW3 + 1 * 1024);
            const float2* Wal = (const float2*)(sW3 + 2 * 1024);
            #pragma unroll
            for (int c = 0; c < C2; ++c) {
                const float cfa = sab[c];
                const float cft = s_stb[t * 33 + c];
                const float cfl = s_sall[c];
                const int idx = c * 16 + y;
                float2 wa = Wab[idx]; S0 = fmaf(cfa, wa.x, S0); S1 = fmaf(cfa, wa.y, S1);
                float2 wt = Wtb[idx]; S0 = fmaf(cft, wt.x, S0); S1 = fmaf(cft, wt.y, S1);
                float2 wl = Wal[idx]; L0 = fmaf(cfl, wl.x, L0); L1 = fmaf(cfl, wl.y, L1);
            }
        }
        const int gbase = (t & 3) * 16;
        #pragma unroll
        for (int h = 0; h < HH; ++h) {
            const int src = gbase + (h >> 1);
            const float sv = (h & 1) ? S1 : S0;
            const float lv = (h & 1) ? L1 : L0;
            pre[h] += __shfl(sv, src, 64) + dxy * __shfl(lv, src, 64);
        }
        // pick up half B's Wt2 contribution (row t*16+y)
        {
            const float* ppr = &sRpp[(t * 16 + y) * 36];
            #pragma unroll
            for (int h4 = 0; h4 < 8; ++h4) {
                const float4 v = *(const float4*)&ppr[4 * h4];
                pre[4*h4+0] += v.x; pre[4*h4+1] += v.y;
                pre[4*h4+2] += v.z; pre[4*h4+3] += v.w;
            }
        }
        // epilogue: bias, relu, dot fcw, wave reduce
        float local = 0.f;
        #pragma unroll
        for (int h = 0; h < HH; ++h) {
            float v = pre[h] + bias[h];
            v = v > 0.f ? v : 0.f;
            local += v * fcw[h];
        }
        #pragma unroll
        for (int off = 32; off > 0; off >>= 1) local += __shfl_down(local, off, 64);
        if (lane == 0) s_red[tid >> 6] = local;
    }
    __syncthreads();  // B6
    if (tid == 0) {
        const float v = s_red[0] + s_red[1] + s_red[2] + s_red[3]
                      + fcb[0] * (1.f / 256.f);
        atomicAdd(out, v);
    }
}

extern "C" void kernel_launch(void* const* d_in, const int* in_sizes, int n_in,
                              void* d_out, int out_size, void* d_ws, size_t ws_size,
                              hipStream_t stream) {
    const float* X    = (const float*)d_in[0];
    const int*   nbrs = (const int*)  d_in[1];
    const float* W1   = (const float*)d_in[2];
    const float* b1   = (const float*)d_in[3];
    const float* W2   = (const float*)d_in[4];
    const float* b2   = (const float*)d_in[5];
    const float* fc_w = (const float*)d_in[6];
    const float* fc_b = (const float*)d_in[7];
    float* outp = (float*)d_out;

    float* F1c  = (float*)d_ws;          // 256*16*16*32 floats = 8 MB
    float* Wsb2 = F1c + 2097152;         // 1024 floats, written by l1 blocks 0,1

    ccn_l1<<<NV, 512, 0, stream>>>(X, nbrs, W1, b1, F1c, outp, W2, Wsb2);
    ccn_l2<<<NV, 512, 0, stream>>>(F1c, nbrs, W2, b2, fc_w, fc_b, outp, Wsb2);
}

// Round 3
// 104.614 us; speedup vs baseline: 1.0855x; 1.0147x over previous
//
#include <hip/hip_runtime.h>

// CCN_2D on MI355X. N=256 vertices, K=16, C0=16, H=32.
// Facts (validated by exact passes R1-R10):
//  * CH rows one-hot => T_t[a][b][c] = Fin[j_t, P_t[a], P_t[b], c].
//  * A = I_16 collapses contract18 to 6 effective weight matrices.
//  * P_t[t] = -1 (no self-loops) => c17 / d_ttt terms vanish.
//  * Layer-1 input is broadcast of X => rank-1 closed form, no gathers.
//  * F1 channel-interleaved: chunk (i*16+q)*128 + c4*16 + p holds channels
//    4c4..4c4+3 of F1[i][p][q][:] (16 B stride on lane-varying p).
// Structure ladder (measured): 2 plain launches beats 3 launches, coop
// launch, and 1 launch w/ device-scope flags. Window = 2x ~43.5us harness
// ws-poison fills (untouchable) + ~19us of VALU-issue-bound kernels.
// R1 post-mortem: SGPR-stream weights (MM_SL) serialize on load latency.
// R2 post-mortem: prep elimination alone is latency-hidden (flat).
// R3: halve the VALU stream via v_pk_fma_f32 (fp32 peak REQUIRES packing;
// hipcc never auto-packs). Matmuls become MM_DS: uniform-address LDS
// ds_read_b128 (broadcast, separate pipe) + pk_fma — ~25 issues/ci vs
// MM_RL's 64. Weights live in LDS as verbatim vectorized copies (no prep);
// Wsb2 still precomputed into ws by l1 blocks 0-1. All packing is over
// independent accumulator chains => per-element op order unchanged.

constexpr int KN = 16, HH = 32, NV = 256, C2 = 32;

typedef float f32x2 __attribute__((ext_vector_type(2)));
typedef float f32x4 __attribute__((ext_vector_type(4)));

__device__ __forceinline__ f32x2 pkfma(f32x2 a, f32x2 b, f32x2 c) {
    f32x2 d;
    asm("v_pk_fma_f32 %0, %1, %2, %3" : "=v"(d) : "v"(a), "v"(b), "v"(c));
    return d;
}
__device__ __forceinline__ f32x2 pkadd(f32x2 a, f32x2 b) {
    f32x2 d;
    asm("v_pk_add_f32 %0, %1, %2" : "=v"(d) : "v"(a), "v"(b));
    return d;
}
__device__ __forceinline__ f32x2 pkmul(f32x2 a, f32x2 b) {
    f32x2 d;
    asm("v_pk_mul_f32 %0, %1, %2" : "=v"(d) : "v"(a), "v"(b));
    return d;
}
__device__ __forceinline__ f32x2 vlo(f32x4 v) { return __builtin_shufflevector(v, v, 0, 1); }
__device__ __forceinline__ f32x2 vhi(f32x4 v) { return __builtin_shufflevector(v, v, 2, 3); }

// ACC2[16] (f32x2, channel-pairs of 32 outputs) += COEF(ci) * W[ci][:],
// W row-major [NC][32] in LDS. Uniform address across the wave => LDS
// broadcast reads (conflict-free, immediate offsets), pk_fma accumulate.
#define MM_DS(WLDS, NC, COEF_EXPR, ACC2) do {                                  \
    const f32x4* W4_ = (const f32x4*)(WLDS);                                   \
    _Pragma("unroll")                                                          \
    for (int ci = 0; ci < (NC); ++ci) {                                        \
        const float cfs_ = (COEF_EXPR);                                        \
        const f32x2 cf2_ = {cfs_, cfs_};                                       \
        _Pragma("unroll")                                                      \
        for (int h4 = 0; h4 < 8; ++h4) {                                       \
            const f32x4 w_ = W4_[ci * 8 + h4];                                 \
            (ACC2)[2*h4+0] = pkfma(cf2_, vlo(w_), (ACC2)[2*h4+0]);             \
            (ACC2)[2*h4+1] = pkfma(cf2_, vhi(w_), (ACC2)[2*h4+1]);             \
        }                                                                      \
    }                                                                          \
} while (0)

// ---------------- layer 1 ----------------
// E1 slices (512 floats each): 0:Wsb 1:Wab 2:W16 3:Wt2(verbatim) 4:Wtb 5:Wal
// pre = vy*(m*Y0.Wsb) + (m^2*Y0).Wab + vy*(Y0.W16) + (16Z2).Wt2v + Z4.Wtb
//       + dxy*Z5.Wal   (x16 folded into the coefficient: pow2, exact)
// Output layout (float4 chunks): F1c chunk index = (i*16+q)*128 + c4*16 + p,
// holding channels c4*4..c4*4+3 of logical F1[i][p][q][:]. (q,p) = (y,x).
__global__ __launch_bounds__(512)
void ccn_l1(const float* __restrict__ X, const int* __restrict__ nbrs,
            const float* __restrict__ W1, const float* __restrict__ bias,
            float* __restrict__ F1c, float* __restrict__ outz,
            const float* __restrict__ W2f, float* __restrict__ Wsb2)
{
    __shared__ float sE1[6 * 512];       // 12 KB
    __shared__ float sPP2[8 * 256 * 4];  // 32 KB, channel-major [h4][cell][4]
    __shared__ float sX[16][20];
    __shared__ float sV[16][164];        // 5 matvec results x 32 per group
    __shared__ int   s_nbi[16];
    __shared__ int   s_nbj[16][17];
    __shared__ int   s_P[16][16];
    __shared__ int   s_vm[16];
    __shared__ float s_m[16];

    const int tid  = threadIdx.x;
    const int i    = ((blockIdx.x & 7) << 5) | (blockIdx.x >> 3);  // XCD swizzle

    if (blockIdx.x == 0 && tid == 0) outz[0] = 0.f;   // zero accumulator for l2

    // blocks 0,1: precompute the one combined layer-2 slice Wsb2 (1024 floats)
    // into the workspace. Bit-exact vs the old in-l2 expression.
    if (blockIdx.x < 2) {
        const int u = (blockIdx.x << 9) | tid;
        float acc = 0.f;
        #pragma unroll
        for (int g = 6; g < 15; ++g) acc += W2f[g * 1024 + u];
        Wsb2[u] = 16.f * W2f[u] + W2f[5 * 1024 + u] + 16.f * acc;
    }

    if (tid < 16) s_nbi[tid] = nbrs[i * 16 + tid];
    __syncthreads();  // B0

    if (tid < 256) {
        const int t = tid >> 4, y = tid & 15;
        const int j = s_nbi[t];
        s_nbj[t][y] = nbrs[j * 16 + y];
        sX[t][y]    = X[j * 16 + y];
    } else {
        const int u = tid - 256;       // E1 entries 0..255
        float acc = 0.f;
        #pragma unroll
        for (int g = 6; g < 15; ++g) acc += W1[g * 512 + u];
        sE1[u]        = 16.f * W1[u] + W1[5 * 512 + u] + 16.f * acc;
        sE1[512 + u]  = W1[512 + u];
        sE1[1024 + u] = W1[15 * 512 + u];
        sE1[1536 + u] = W1[2 * 512 + u];
        sE1[2048 + u] = W1[3 * 512 + u];
        sE1[2560 + u] = W1[4 * 512 + u];
    }
    __syncthreads();  // B1

    if (tid < 256) {
        const int t = tid >> 4, y = tid & 15;
        const int tgt = s_nbi[y];
        int p = -1;
        #pragma unroll
        for (int q = 0; q < 16; ++q) if (s_nbj[t][q] == tgt) p = q;
        s_P[t][y] = p;
        unsigned long long bal = __ballot(p >= 0);
        if (y == 0) {
            int vm = (int)((bal >> ((t & 3) * 16)) & 0xFFFFull);
            s_vm[t] = vm;
            s_m[t]  = (float)__popc(vm);
        }
    } else {
        const int u = tid;             // E1 entries 256..511
        float acc = 0.f;
        #pragma unroll
        for (int g = 6; g < 15; ++g) acc += W1[g * 512 + u];
        sE1[u]        = 16.f * W1[u] + W1[5 * 512 + u] + 16.f * acc;
        sE1[512 + u]  = W1[512 + u];
        sE1[1024 + u] = W1[15 * 512 + u];
        sE1[1536 + u] = W1[2 * 512 + u];
        sE1[2048 + u] = W1[3 * 512 + u];
        sE1[2560 + u] = W1[4 * 512 + u];
    }
    __syncthreads();  // B2

    if (tid < 256) {
        // ---- half A: Z4/Z5 + 5 cooperative matvecs (lane y -> h=2y,2y+1) ----
        const int t = tid >> 4, y = tid & 15, x = t;
        float Y0[16];
        #pragma unroll
        for (int c4 = 0; c4 < 4; ++c4) {
            float4 v = *(const float4*)&sX[t][4 * c4];
            Y0[4*c4+0] = v.x; Y0[4*c4+1] = v.y; Y0[4*c4+2] = v.z; Y0[4*c4+3] = v.w;
        }
        f32x2 Z42[8], Z52[8];
        #pragma unroll
        for (int c = 0; c < 8; ++c) { Z42[c] = (f32x2){0.f,0.f}; Z52[c] = (f32x2){0.f,0.f}; }
        #pragma unroll
        for (int tp = 0; tp < 16; ++tp) {
            const int vm = s_vm[tp];
            const float mt = s_m[tp];
            const float fb = ((vm >> x) & 1) ? mt : 0.f;
            const float f5 = mt * mt;
            const f32x2 fb2 = {fb, fb};
            const f32x2 f52 = {f5, f5};
            #pragma unroll
            for (int c4 = 0; c4 < 4; ++c4) {
                const f32x4 v = *(const f32x4*)&sX[tp][4 * c4];
                Z42[2*c4+0] = pkfma(fb2, vlo(v), Z42[2*c4+0]);
                Z42[2*c4+1] = pkfma(fb2, vhi(v), Z42[2*c4+1]);
                Z52[2*c4+0] = pkfma(f52, vlo(v), Z52[2*c4+0]);
                Z52[2*c4+1] = pkfma(f52, vhi(v), Z52[2*c4+1]);
            }
        }
        const float m = s_m[t];
        float v0a=0.f,v0b=0.f,v1a=0.f,v1b=0.f,v2a=0.f,v2b=0.f;
        float v3a=0.f,v3b=0.f,v4a=0.f,v4b=0.f;
        const float2* Wsb = (const float2*)(sE1 + 0 * 512);
        const float2* Wab = (const float2*)(sE1 + 1 * 512);
        const float2* W16 = (const float2*)(sE1 + 2 * 512);
        const float2* Wtb = (const float2*)(sE1 + 4 * 512);
        const float2* Wal = (const float2*)(sE1 + 5 * 512);
        #pragma unroll
        for (int c = 0; c < 16; ++c) {
            const float cf0 = m * Y0[c];
            const float cf1 = m * cf0;
            const float cf2 = Y0[c];
            const float cf3 = Z42[c >> 1][c & 1];
            const float cf4 = Z52[c >> 1][c & 1];
            const int idx = c * 16 + y;
            float2 w0 = Wsb[idx]; v0a = fmaf(cf0, w0.x, v0a); v0b = fmaf(cf0, w0.y, v0b);
            float2 w1 = Wab[idx]; v1a = fmaf(cf1, w1.x, v1a); v1b = fmaf(cf1, w1.y, v1b);
            float2 w2 = W16[idx]; v2a = fmaf(cf2, w2.x, v2a); v2b = fmaf(cf2, w2.y, v2b);
            float2 w3 = Wtb[idx]; v3a = fmaf(cf3, w3.x, v3a); v3b = fmaf(cf3, w3.y, v3b);
            float2 w4 = Wal[idx]; v4a = fmaf(cf4, w4.x, v4a); v4b = fmaf(cf4, w4.y, v4b);
        }
        *(float2*)&sV[t][0 * 32 + 2 * y] = make_float2(v0a, v0b);
        *(float2*)&sV[t][1 * 32 + 2 * y] = make_float2(v1a, v1b);
        *(float2*)&sV[t][2 * 32 + 2 * y] = make_float2(v2a, v2b);
        *(float2*)&sV[t][3 * 32 + 2 * y] = make_float2(v3a, v3b);
        *(float2*)&sV[t][4 * 32 + 2 * y] = make_float2(v4a, v4b);
    } else {
        // ---- half B: Z2 (packed) + Wt2 MM_DS, park channel-major ----
        const int w = tid - 256;
        const int t = w >> 4, y = w & 15, x = t;
        f32x2 Z22[8];
        #pragma unroll
        for (int c = 0; c < 8; ++c) Z22[c] = (f32x2){0.f,0.f};
        #pragma unroll
        for (int tp = 0; tp < 16; ++tp) {
            const int vm = s_vm[tp];
            const float f2 = (float)((vm >> x) & (vm >> y) & 1);
            const f32x2 f22 = {f2, f2};
            #pragma unroll
            for (int c4 = 0; c4 < 4; ++c4) {
                const f32x4 v = *(const f32x4*)&sX[tp][4 * c4];
                Z22[2*c4+0] = pkfma(f22, vlo(v), Z22[2*c4+0]);
                Z22[2*c4+1] = pkfma(f22, vhi(v), Z22[2*c4+1]);
            }
        }
        f32x2 pp2[16];
        #pragma unroll
        for (int h = 0; h < 16; ++h) pp2[h] = (f32x2){0.f,0.f};
        // Wt2 = 16*W1[2*512+..] (slot 3 verbatim); fold the pow2 into cf.
        MM_DS(sE1 + 3 * 512, 16, 16.f * Z22[ci >> 1][ci & 1], pp2);
        // park: cell keyed as (y_out*16 + x_out) = (y*16 + t) so reader
        // (q,p) hits (q*16+p).
        const int cell = y * 16 + t;
        #pragma unroll
        for (int h4 = 0; h4 < 8; ++h4) {
            const int base = (h4 * 256 + cell) * 4;
            *(f32x2*)&sPP2[base]     = pp2[2*h4+0];
            *(f32x2*)&sPP2[base + 2] = pp2[2*h4+1];
        }
    }
    __syncthreads();  // B3 (sV + sPP2 + s_P ready) — final barrier

    if (tid < 256) {
        // output thread (q,p) computes cell (x=p, y=q) and stores directly:
        // chunk (i*16+q)*128 + h4*16 + p  -> p lane-varying, 256 B coalesced.
        const int q = tid >> 4, p = tid & 15;
        const float vy  = (s_P[p][q] >= 0) ? 1.f : 0.f;
        const float dxy = (p == q) ? 1.f : 0.f;
        const f32x2 vy2 = {vy, vy}, dxy2 = {dxy, dxy};
        float4* F4 = (float4*)F1c;
        const size_t basec = ((size_t)i * 16 + q) * 128 + p;
        #pragma unroll
        for (int h4 = 0; h4 < 8; ++h4) {
            const f32x4 V0 = *(const f32x4*)&sV[p][0 * 32 + 4 * h4];
            const f32x4 V1 = *(const f32x4*)&sV[p][1 * 32 + 4 * h4];
            const f32x4 V2 = *(const f32x4*)&sV[p][2 * 32 + 4 * h4];
            const f32x4 V3 = *(const f32x4*)&sV[p][3 * 32 + 4 * h4];
            const f32x4 V4 = *(const f32x4*)&sV[p][4 * 32 + 4 * h4];
            const f32x4 PP = *(const f32x4*)&sPP2[(h4 * 256 + q * 16 + p) * 4];
            const f32x2 blo = *(const f32x2*)&bias[4 * h4];
            const f32x2 bhi = *(const f32x2*)&bias[4 * h4 + 2];
            // order per element: vy*(V0+V2) + V1 + V3 + dxy*V4 + PP + bias
            f32x2 slo = pkadd(vlo(V0), vlo(V2));
            slo = pkfma(vy2, slo, vlo(V1));
            slo = pkadd(slo, vlo(V3));
            slo = pkfma(dxy2, vlo(V4), slo);
            slo = pkadd(slo, vlo(PP));
            slo = pkadd(slo, blo);
            f32x2 shi = pkadd(vhi(V0), vhi(V2));
            shi = pkfma(vy2, shi, vhi(V1));
            shi = pkadd(shi, vhi(V3));
            shi = pkfma(dxy2, vhi(V4), shi);
            shi = pkadd(shi, vhi(PP));
            shi = pkadd(shi, bhi);
            F4[basec + h4 * 16] = make_float4(fmaxf(slo.x, 0.f), fmaxf(slo.y, 0.f),
                                              fmaxf(shi.x, 0.f), fmaxf(shi.y, 0.f));
        }
    }
}

// ---------------- layer 2 ----------------
// MM slices in LDS (verbatim vectorized copies, no prep):
//   sMM[0]:Wsb2 (from ws)  sMM[1]:W16=W2+15*1024  sMM[2]:Wt2=W2+2*1024
//   sW3[0]:Wab=W2+1024  sW3[1]:Wtb=W2+3*1024  sW3[2]:Wal=W2+4*1024
// F1c chunk (j*16+q)*128 + c4*16 + p = channels 4c4..4c4+3 of F1[j][p][q][:].
__global__ __launch_bounds__(512)
void ccn_l2(const float* __restrict__ F1c, const int* __restrict__ nbrs,
            const float* __restrict__ W2, const float* __restrict__ bias,
            const float* __restrict__ fcw, const float* __restrict__ fcb,
            float* __restrict__ out, const float* __restrict__ Wsb2)
{
    __shared__ float sMM[3 * 1024];    // 12 KB: MM weights (uniform ds reads)
    __shared__ float sW3[3 * 1024];    // 12 KB: epilogue matvec weights
    __shared__ float sRpp[256 * 36];   // 36 KB: R rows, then half-B pp results
    __shared__ float s_stb[16 * 33];
    __shared__ float s_sall[C2];
    __shared__ int   s_nbi[16];
    __shared__ int   s_PQ[16 * 17];    // nbj, then overwritten with P (wave-local)
    __shared__ float s_red[4];

    const int tid  = threadIdx.x;
    const int i    = ((blockIdx.x & 7) << 5) | (blockIdx.x >> 3);  // XCD swizzle
    const int lane = tid & 63;
    const f32x4* F4 = (const f32x4*)F1c;

    if (tid < 16) s_nbi[tid] = nbrs[i * 16 + tid];
    __syncthreads();  // B0

    if (tid < 256) {
        const int t = tid >> 4, y = tid & 15;
        const int j = s_nbi[t];
        s_PQ[t * 17 + y] = nbrs[j * 16 + y];
    } else {
        const int w = tid - 256;
        ((f32x4*)sMM)[w]       = ((const f32x4*)Wsb2)[w];
        ((f32x4*)sMM)[256 + w] = ((const f32x4*)(W2 + 15 * 1024))[w];
        ((f32x4*)sMM)[512 + w] = ((const f32x4*)(W2 +  2 * 1024))[w];
        ((f32x4*)sW3)[w]       = ((const f32x4*)(W2 +  1 * 1024))[w];
        ((f32x4*)sW3)[256 + w] = ((const f32x4*)(W2 +  3 * 1024))[w];
        ((f32x4*)sW3)[512 + w] = ((const f32x4*)(W2 +  4 * 1024))[w];
    }
    __syncthreads();  // B1

    if (tid < 256) {
        const int t = tid >> 4, y = tid & 15;
        const int tgt = s_nbi[y];
        int p = -1;
        #pragma unroll
        for (int q = 0; q < 16; ++q) if (s_PQ[t * 17 + q] == tgt) p = q;
        s_PQ[t * 17 + y] = p;   // overwrite: reads above precede write (wave lockstep)
    }
    __syncthreads();  // B2

    f32x2 pre2[16];
    float sab[C2];
    f32x2 pp2[16];

    if (tid < 256) {
        // ---- half A: R gather (packed) + Wsb/W16 MM_DS ----
        const int t = tid >> 4, y = tid & 15;
        const int j = s_nbi[t];
        const int p = s_PQ[t * 17 + y];
        const float mp = (p >= 0) ? 1.f : 0.f;
        const int pc = p >= 0 ? p : 0;
        const size_t jbase = (size_t)j * 2048;   // 16*128 chunks per tile

        f32x2 R2[16];
        #pragma unroll
        for (int c = 0; c < 16; ++c) R2[c] = (f32x2){0.f, 0.f};
        #pragma unroll
        for (int b = 0; b < 16; ++b) {
            const int q = s_PQ[t * 17 + b];
            const float mm = (q >= 0) ? mp : 0.f;
            const f32x2 mm2 = {mm, mm};
            const int qc = q >= 0 ? q : 0;
            const size_t rb = jbase + (size_t)qc * 128 + pc;
            #pragma unroll
            for (int c4 = 0; c4 < 8; ++c4) {
                const f32x4 v = F4[rb + c4 * 16];
                R2[2*c4+0] = pkfma(mm2, vlo(v), R2[2*c4+0]);
                R2[2*c4+1] = pkfma(mm2, vhi(v), R2[2*c4+1]);
            }
        }
        {
            float* dst = &sRpp[(t * 16 + y) * 36];
            #pragma unroll
            for (int c4 = 0; c4 < 8; ++c4) {
                *(f32x2*)&dst[4*c4]     = R2[2*c4+0];
                *(f32x2*)&dst[4*c4 + 2] = R2[2*c4+1];
            }
        }

        #pragma unroll
        for (int h = 0; h < 16; ++h) pre2[h] = (f32x2){0.f, 0.f};
        MM_DS(sMM, 32, R2[ci >> 1][ci & 1], pre2);         // Wsb^T R

        #pragma unroll
        for (int c = 0; c < C2; ++c) {
            float s = R2[c >> 1][c & 1];
            s += __shfl_xor(s, 1);
            s += __shfl_xor(s, 2);
            s += __shfl_xor(s, 4);
            s += __shfl_xor(s, 8);
            sab[c] = s;
        }

        f32x2 D2[16];
        {
            const f32x2 mp2 = {mp, mp};
            const size_t db = jbase + (size_t)pc * 128 + pc;
            #pragma unroll
            for (int c4 = 0; c4 < 8; ++c4) {
                const f32x4 v = F4[db + c4 * 16];
                D2[2*c4+0] = pkmul(mp2, vlo(v));
                D2[2*c4+1] = pkmul(mp2, vhi(v));
            }
        }
        MM_DS(sMM + 1024, 32, D2[ci >> 1][ci & 1], pre2);  // W16^T D
    } else {
        // ---- half B: ST gather (packed) + Wt2 MM_DS ----
        const int w = tid - 256;
        const int g = w >> 4, l = w & 15;              // output (x=l, y=g)
        f32x2 ST2[16];
        #pragma unroll
        for (int c = 0; c < 16; ++c) ST2[c] = (f32x2){0.f, 0.f};
        #pragma unroll
        for (int tp = 0; tp < 16; ++tp) {
            const int jt = s_nbi[tp];
            const int py = s_PQ[tp * 17 + g];          // group-uniform
            const int px = s_PQ[tp * 17 + l];          // lane-varying
            const float mm = (px >= 0 && py >= 0) ? 1.f : 0.f;
            const f32x2 mm2 = {mm, mm};
            const int pyc = py >= 0 ? py : 0;
            const int pxc = px >= 0 ? px : 0;
            const size_t rb = (size_t)jt * 2048 + (size_t)pyc * 128 + pxc;
            #pragma unroll
            for (int c4 = 0; c4 < 8; ++c4) {
                const f32x4 v = F4[rb + c4 * 16];
                ST2[2*c4+0] = pkfma(mm2, vlo(v), ST2[2*c4+0]);
                ST2[2*c4+1] = pkfma(mm2, vhi(v), ST2[2*c4+1]);
            }
        }
        #pragma unroll
        for (int h = 0; h < 16; ++h) pp2[h] = (f32x2){0.f, 0.f};
        // Wt2 = 16*(W2+2*1024); fold the pow2 into the coefficient (exact).
        MM_DS(sMM + 2048, 32, 16.f * ST2[ci >> 1][ci & 1], pp2);   // Wt2^T ST
    }
    __syncthreads();  // B3  (sR rows complete)

    if (tid < 256) {
        // stb[x2][c] = sum_t R[t][x2][c]
        #pragma unroll
        for (int k = 0; k < 2; ++k) {
            const int x2 = (tid >> 5) + 8 * k;
            const int c = tid & 31;
            float s = 0.f;
            #pragma unroll
            for (int tt = 0; tt < 16; ++tt) s += sRpp[(tt * 16 + x2) * 36 + c];
            s_stb[x2 * 33 + c] = s;
        }
    }
    __syncthreads();  // B4  (stb complete; sR now dead)

    if (tid < 256) {
        if (tid < 32) {
            float s = 0.f;
            #pragma unroll
            for (int x2 = 0; x2 < 16; ++x2) s += s_stb[x2 * 33 + tid];
            s_sall[tid] = s;
        }
    } else {
        // half B parks its pp into the dead sR buffer at row x*16+y = l*16+g
        const int w = tid - 256;
        const int g = w >> 4, l = w & 15;
        float* dst = &sRpp[(l * 16 + g) * 36];
        #pragma unroll
        for (int h4 = 0; h4 < 8; ++h4) {
            *(f32x2*)&dst[4*h4]     = pp2[2*h4+0];
            *(f32x2*)&dst[4*h4 + 2] = pp2[2*h4+1];
        }
    }
    __syncthreads();  // B5

    if (tid < 256) {
        const int t = tid >> 4, y = tid & 15, x = t;
        const float dxy = (x == y) ? 1.f : 0.f;
        // cooperative matvecs Wab/Wtb/Wal (lane y -> h=2y,2y+1), combine via shfl
        float S0 = 0.f, S1 = 0.f, L0 = 0.f, L1 = 0.f;
        {
            const float2* Wab = (const float2*)(sW3 + 0 * 1024);
            const float2* Wtb = (const float2*)(sW3 + 1 * 1024);
            const float2* Wal = (const float2*)(sW3 + 2 * 1024);
            #pragma unroll
            for (int c = 0; c < C2; ++c) {
                const float cfa = sab[c];
                const float cft = s_stb[t * 33 + c];
                const float cfl = s_sall[c];
                const int idx = c * 16 + y;
                float2 wa = Wab[idx]; S0 = fmaf(cfa, wa.x, S0); S1 = fmaf(cfa, wa.y, S1);
                float2 wt = Wtb[idx]; S0 = fmaf(cft, wt.x, S0); S1 = fmaf(cft, wt.y, S1);
                float2 wl = Wal[idx]; L0 = fmaf(cfl, wl.x, L0); L1 = fmaf(cfl, wl.y, L1);
            }
        }
        const int gbase = (t & 3) * 16;
        #pragma unroll
        for (int h = 0; h < HH; ++h) {
            const int src = gbase + (h >> 1);
            const float sv = (h & 1) ? S1 : S0;
            const float lv = (h & 1) ? L1 : L0;
            pre2[h >> 1][h & 1] += __shfl(sv, src, 64) + dxy * __shfl(lv, src, 64);
        }
        // pick up half B's Wt2 contribution (row t*16+y)
        {
            const float* ppr = &sRpp[(t * 16 + y) * 36];
            #pragma unroll
            for (int h4 = 0; h4 < 8; ++h4) {
                const f32x2 a = *(const f32x2*)&ppr[4*h4];
                const f32x2 b = *(const f32x2*)&ppr[4*h4 + 2];
                pre2[2*h4+0] = pkadd(pre2[2*h4+0], a);
                pre2[2*h4+1] = pkadd(pre2[2*h4+1], b);
            }
        }
        // epilogue: bias, relu, dot fcw, wave reduce
        float local = 0.f;
        #pragma unroll
        for (int h = 0; h < HH; ++h) {
            float v = pre2[h >> 1][h & 1] + bias[h];
            v = v > 0.f ? v : 0.f;
            local += v * fcw[h];
        }
        #pragma unroll
        for (int off = 32; off > 0; off >>= 1) local += __shfl_down(local, off, 64);
        if (lane == 0) s_red[tid >> 6] = local;
    }
    __syncthreads();  // B6
    if (tid == 0) {
        const float v = s_red[0] + s_red[1] + s_red[2] + s_red[3]
                      + fcb[0] * (1.f / 256.f);
        atomicAdd(out, v);
    }
}

extern "C" void kernel_launch(void* const* d_in, const int* in_sizes, int n_in,
                              void* d_out, int out_size, void* d_ws, size_t ws_size,
                              hipStream_t stream) {
    const float* X    = (const float*)d_in[0];
    const int*   nbrs = (const int*)  d_in[1];
    const float* W1   = (const float*)d_in[2];
    const float* b1   = (const float*)d_in[3];
    const float* W2   = (const float*)d_in[4];
    const float* b2   = (const float*)d_in[5];
    const float* fc_w = (const float*)d_in[6];
    const float* fc_b = (const float*)d_in[7];
    float* outp = (float*)d_out;

    float* F1c  = (float*)d_ws;          // 256*16*16*32 floats = 8 MB
    float* Wsb2 = F1c + 2097152;         // 1024 floats, written by l1 blocks 0,1

    ccn_l1<<<NV, 512, 0, stream>>>(X, nbrs, W1, b1, F1c, outp, W2, Wsb2);
    ccn_l2<<<NV, 512, 0, stream>>>(F1c, nbrs, W2, b2, fc_w, fc_b, outp, Wsb2);
}